// Round 8
// baseline (7863.873 us; speedup 1.0000x reference)
//
#include <hip/hip_runtime.h>
#include <cmath>

#define B 128
#define T 128
#define H 512
#define TGT 32

#define SCOPE_AGENT __HIP_MEMORY_SCOPE_AGENT

struct Args {
  const float *x, *eWih0, *eWhh0, *eWih1, *eWhh1, *ebih, *ebhh;
  const float *dWih0, *dWihr, *dWhh, *dbih, *dbhh, *linW, *linb;
  float *dst;    // dstate [2 parity][4 layer][B][H]  -- agent-scope atomic access ONLY
  float *xing;   // [2][B][4]                          -- agent-scope atomic access ONLY
  float *l0;     // [T][B][1024]  (plain cached; fenced at grid barriers)
  unsigned *ctr; // [64]: 0..31 E0+E1 (dir*16+pr, +8 for chain B; E1 reuses at +2048),
                 //       32..39 DEC, 48 grid
  float *out;    // [B][TGT]
};

// ---------------------------------------------------------------------------
__global__ void kinit(float* __restrict__ st, unsigned* __restrict__ ctr) {
  int idx = blockIdx.x * 256 + threadIdx.x;
  for (int i = idx; i < 4 * B * H; i += 256 * 256) st[i] = 0.f;  // parity-0 state
  if (idx < 64) ctr[idx] = 0u;
}

// --------------------------- sync primitives -------------------------------
__device__ __forceinline__ void bumpR(unsigned* c) {
  __syncthreads();  // all waves' agent-scope stores drained to MALL
  if (threadIdx.x == 0)
    __hip_atomic_fetch_add(c, 1u, __ATOMIC_RELAXED, SCOPE_AGENT);
}
__device__ __forceinline__ void waitcR(unsigned* c, unsigned tgt) {
  if (threadIdx.x == 0)
    while (__hip_atomic_load(c, __ATOMIC_RELAXED, SCOPE_AGENT) < tgt)
      __builtin_amdgcn_s_sleep(2);
  __syncthreads();
}
// grid barriers: full release/acquire (flush/inv L2) for the plain-cached l0/G1
__device__ __forceinline__ void bumpF(unsigned* c) {
  __syncthreads();
  if (threadIdx.x == 0)
    __hip_atomic_fetch_add(c, 1u, __ATOMIC_RELEASE, SCOPE_AGENT);
}
__device__ __forceinline__ void waitcF(unsigned* c, unsigned tgt) {
  if (threadIdx.x == 0) {
    while (__hip_atomic_load(c, __ATOMIC_RELAXED, SCOPE_AGENT) < tgt)
      __builtin_amdgcn_s_sleep(2);
    __builtin_amdgcn_fence(__ATOMIC_ACQUIRE, "agent");
  }
  __syncthreads();
}

// --------------------------- staging helpers -------------------------------
__device__ __forceinline__ void stC(float* p, float v) {
  __hip_atomic_store(p, v, __ATOMIC_RELAXED, SCOPE_AGENT);
}
__device__ __forceinline__ float ldC(const float* p) {
  return __hip_atomic_load(p, __ATOMIC_RELAXED, SCOPE_AGENT);
}

// generic rolled stage (G1 only; not latency-critical)
template <int ROWLEN, int GSTRIDE>
__device__ __forceinline__ void stage(const float* __restrict__ g,
                                      float* __restrict__ l, int rows, int lstride) {
  int total = rows * ROWLEN;
  for (int idx = (int)threadIdx.x * 4; idx < total; idx += 1024) {
    int r = idx / ROWLEN, k = idx - r * ROWLEN;
    float4 v = *(const float4*)(g + (size_t)r * GSTRIDE + k);
    *(float4*)(l + r * lstride + k) = v;
  }
}

// 16 rows x 512 floats, plain cached loads (weights), fully unrolled
__device__ __forceinline__ void stage16(const float* __restrict__ g,
                                        float* __restrict__ l) {
  const int t = threadIdx.x;
  const int r0 = t >> 7, k0 = (t & 127) * 4;
  float4 v[8];
#pragma unroll
  for (int i = 0; i < 8; i++)
    v[i] = *(const float4*)(g + (size_t)(r0 + 2 * i) * 512 + k0);
#pragma unroll
  for (int i = 0; i < 8; i++)
    *(float4*)(l + (r0 + 2 * i) * 516 + k0) = v[i];
}

// 16 rows x 512 floats, DEVICE-COHERENT (8B agent atomics), fully unrolled
__device__ __forceinline__ void stageC16(const float* __restrict__ g,
                                         float* __restrict__ l) {
  const unsigned long long* gu = (const unsigned long long*)g;
  unsigned long long* lu = (unsigned long long*)l;
  const int t = threadIdx.x;
  unsigned long long v[16];
#pragma unroll
  for (int i = 0; i < 16; i++)
    v[i] = __hip_atomic_load(gu + (size_t)i * 256 + t, __ATOMIC_RELAXED, SCOPE_AGENT);
#pragma unroll
  for (int i = 0; i < 16; i++)
    lu[i * 258 + t] = v[i];
}

// 8 rows x 512 floats, DEVICE-COHERENT, fully unrolled
__device__ __forceinline__ void stageC8(const float* __restrict__ g,
                                        float* __restrict__ l) {
  const unsigned long long* gu = (const unsigned long long*)g;
  unsigned long long* lu = (unsigned long long*)l;
  const int t = threadIdx.x;
  unsigned long long v[8];
#pragma unroll
  for (int i = 0; i < 8; i++)
    v[i] = __hip_atomic_load(gu + (size_t)i * 256 + t, __ATOMIC_RELAXED, SCOPE_AGENT);
#pragma unroll
  for (int i = 0; i < 8; i++)
    lu[i * 258 + t] = v[i];
}

#define DOT4(accv, hv, wv) accv += hv.x*wv.x + hv.y*wv.y + hv.z*wv.z + hv.w*wv.w
#define DOT4B(accv, hv, wv, iv, uv)                                       \
  accv += hv.x*wv.x + hv.y*wv.y + hv.z*wv.z + hv.w*wv.w                   \
        + iv.x*uv.x + iv.y*uv.y + iv.z*uv.z + iv.w*uv.w

// 4-row x 16-col tile, 16-way k-split. hb/wb pre-offset by (row4)*516 + kg*4.
// Lane kg owns output (rr=kg>>2, cc=kg&3). k coverage: 16kg*4 = 64/iter, 8 iters.
__device__ __forceinline__ float dotK16(const float* hb, const float* wb, int kg) {
  float acc[4][4];
#pragma unroll
  for (int rr = 0; rr < 4; rr++)
#pragma unroll
    for (int cc = 0; cc < 4; cc++) acc[rr][cc] = 0.f;
#pragma unroll
  for (int i = 0; i < 8; i++) {
    const int k = i * 64;
    float4 h0 = *(const float4*)(hb + k);
    float4 h1 = *(const float4*)(hb + 516 + k);
    float4 h2 = *(const float4*)(hb + 1032 + k);
    float4 h3 = *(const float4*)(hb + 1548 + k);
    float4 w0 = *(const float4*)(wb + k);
    float4 w1 = *(const float4*)(wb + 516 + k);
    float4 w2 = *(const float4*)(wb + 1032 + k);
    float4 w3 = *(const float4*)(wb + 1548 + k);
    DOT4(acc[0][0],h0,w0); DOT4(acc[0][1],h0,w1); DOT4(acc[0][2],h0,w2); DOT4(acc[0][3],h0,w3);
    DOT4(acc[1][0],h1,w0); DOT4(acc[1][1],h1,w1); DOT4(acc[1][2],h1,w2); DOT4(acc[1][3],h1,w3);
    DOT4(acc[2][0],h2,w0); DOT4(acc[2][1],h2,w1); DOT4(acc[2][2],h2,w2); DOT4(acc[2][3],h2,w3);
    DOT4(acc[3][0],h3,w0); DOT4(acc[3][1],h3,w1); DOT4(acc[3][2],h3,w2); DOT4(acc[3][3],h3,w3);
  }
#pragma unroll
  for (int rr = 0; rr < 4; rr++)
#pragma unroll
    for (int cc = 0; cc < 4; cc++) {
      float v = acc[rr][cc];
      v += __shfl_xor(v, 1); v += __shfl_xor(v, 2);
      v += __shfl_xor(v, 4); v += __shfl_xor(v, 8);
      acc[rr][cc] = v;
    }
  float sv = 0.f;
#pragma unroll
  for (int rr = 0; rr < 4; rr++)
#pragma unroll
    for (int cc = 0; cc < 4; cc++)
      sv = (kg == rr * 4 + cc) ? acc[rr][cc] : sv;
  return sv;
}

// ---------------------------------------------------------------------------
__global__ __launch_bounds__(256, 1) void birnn_all(Args a) {
  __shared__ __align__(16) float sm[33088];   // 132352 B, unioned per phase
  const int tid = threadIdx.x;
  const int bx = blockIdx.x;

  // E-phase decomposition (both layers): block (dir=bx>>7, pr=(bx>>4)&7, ntile=bx&15).
  // TWO same-dir chains per block: A = batches pr*8..+7, B = +64. Shared weights.
  // 8b x 32n per chain; thread (kg=tid&15, ni=(tid>>4)&7, bi=tid>>7):
  // row = bi*4+(kg>>2), col = n0+ni*4+(kg&3). Chain A's handoff wait hides
  // under chain B's stage+compute and vice versa. 16 members/chain.
  const int dirE = bx >> 7, prE = (bx >> 4) & 7, ntE = bx & 15;
  const int b0A = prE * 8, b0B = prE * 8 + 64, n0E = ntE * 32;
  const int kgE = tid & 15, niE = (tid >> 4) & 7, biE = tid >> 7;
  const int nlaneE = n0E + niE * 4 + (kgE & 3);
  const int rlocE  = biE * 4 + (kgE >> 2);
  const int hoffE = biE * 4 * 516 + kgE * 4;
  const int woffE = niE * 4 * 516 + kgE * 4;

  //========================= ENCODER LAYER 0 ================================
  {
    float* wl  = sm;           // [32][516] eWhh0[dirE] rows n0E..n0E+31
    float* hlA = sm + 16512;   // [8][516]
    float* hlB = sm + 20640;   // [8][516]
    unsigned* cA = a.ctr + dirE * 16 + prE;
    unsigned* cB = a.ctr + dirE * 16 + prE + 8;

    stage16(a.eWhh0 + (size_t)(dirE * H + n0E) * H, wl);
    stage16(a.eWhh0 + (size_t)(dirE * H + n0E + 16) * H, wl + 16 * 516);

    float wx0 = a.eWih0[(dirE * H + nlaneE) * 3 + 0];
    float wx1 = a.eWih0[(dirE * H + nlaneE) * 3 + 1];
    float wx2 = a.eWih0[(dirE * H + nlaneE) * 3 + 2];
    float bias = a.ebih[dirE * H + nlaneE] + a.ebhh[dirE * H + nlaneE];

    for (int s = 0; s < T; s++) {
      int t_ = dirE ? (T - 1 - s) : s;
      const float* xrA = a.x + ((size_t)(b0A + rlocE) * T + t_) * 3;
      const float* xrB = a.x + ((size_t)(b0B + rlocE) * T + t_) * 3;
      float aA = bias + xrA[0] * wx0 + xrA[1] * wx1 + xrA[2] * wx2;
      float aB = bias + xrB[0] * wx0 + xrB[1] * wx1 + xrB[2] * wx2;

      // ---- chain A ----
      if (s) waitcR(cA, 16u * s); else __syncthreads();
      stageC8(a.dst + ((size_t)((s & 1) * 4 + dirE) * B + b0A) * H, hlA);
      __syncthreads();
      float oA = tanhf(aA + dotK16(hlA + hoffE, wl + woffE, kgE));
      stC(a.dst + ((size_t)(((s + 1) & 1) * 4 + dirE) * B + (b0A + rlocE)) * H + nlaneE, oA);
      bumpR(cA);
      a.l0[((size_t)t_ * B + (b0A + rlocE)) * 1024 + dirE * H + nlaneE] = oA;

      // ---- chain B (wait hidden under chain A's work) ----
      if (s) waitcR(cB, 16u * s);
      stageC8(a.dst + ((size_t)((s & 1) * 4 + dirE) * B + b0B) * H, hlB);
      __syncthreads();
      float oB = tanhf(aB + dotK16(hlB + hoffE, wl + woffE, kgE));
      stC(a.dst + ((size_t)(((s + 1) & 1) * 4 + dirE) * B + (b0B + rlocE)) * H + nlaneE, oB);
      bumpR(cB);
      a.l0[((size_t)t_ * B + (b0B + rlocE)) * 1024 + dirE * H + nlaneE] = oB;
    }
  }
  { unsigned* g = a.ctr + 48; bumpF(g); waitcF(g, 256u); }  // grid barrier 1

  //===================== ENC1 INPUT PROJECTION (in-place G1) ================
  {
    float* xl = sm;          // [16][1028]
    float* wl = sm + 16448;  // [64][260]
    const int kg = tid & 3;
    const int ci = (tid >> 2) & 15;
    const int ri = tid >> 6;
    for (int rt = 0; rt < 4; rt++) {
      int row0 = (bx * 4 + rt) * 16;
      __syncthreads();
      stage<1024, 1024>(a.l0 + (size_t)row0 * 1024, xl, 16, 1028);
      __syncthreads();
      for (int nc = 0; nc < 16; nc++) {
        const int nb = nc * 64 + ci * 4 + kg;
        float biasv = a.ebih[(2 + (nb >> 9)) * H + (nb & 511)] +
                      a.ebhh[(2 + (nb >> 9)) * H + (nb & 511)];
        float acc[4][4];
#pragma unroll
        for (int rr = 0; rr < 4; rr++)
#pragma unroll
          for (int cc = 0; cc < 4; cc++) acc[rr][cc] = 0.f;

        for (int kp = 0; kp < 4; kp++) {
          __syncthreads();
          stage<256, 1024>(a.eWih1 + (size_t)(nc * 64) * 1024 + kp * 256, wl, 64, 260);
          __syncthreads();
          const float* xp0 = xl + (ri * 4 + 0) * 1028 + kp * 256 + kg * 4;
          const float* xp1 = xp0 + 1028;
          const float* xp2 = xp0 + 2 * 1028;
          const float* xp3 = xp0 + 3 * 1028;
          const float* wq0 = wl + (ci * 4 + 0) * 260 + kg * 4;
          const float* wq1 = wq0 + 260;
          const float* wq2 = wq0 + 2 * 260;
          const float* wq3 = wq0 + 3 * 260;
#pragma unroll 4
          for (int i = 0; i < 16; i++) {
            const int k = i * 16;
            float4 x0 = *(const float4*)(xp0 + k);
            float4 x1 = *(const float4*)(xp1 + k);
            float4 x2 = *(const float4*)(xp2 + k);
            float4 x3 = *(const float4*)(xp3 + k);
            float4 w0 = *(const float4*)(wq0 + k);
            float4 w1 = *(const float4*)(wq1 + k);
            float4 w2 = *(const float4*)(wq2 + k);
            float4 w3 = *(const float4*)(wq3 + k);
            DOT4(acc[0][0], x0, w0); DOT4(acc[0][1], x0, w1); DOT4(acc[0][2], x0, w2); DOT4(acc[0][3], x0, w3);
            DOT4(acc[1][0], x1, w0); DOT4(acc[1][1], x1, w1); DOT4(acc[1][2], x1, w2); DOT4(acc[1][3], x1, w3);
            DOT4(acc[2][0], x2, w0); DOT4(acc[2][1], x2, w1); DOT4(acc[2][2], x2, w2); DOT4(acc[2][3], x2, w3);
            DOT4(acc[3][0], x3, w0); DOT4(acc[3][1], x3, w1); DOT4(acc[3][2], x3, w2); DOT4(acc[3][3], x3, w3);
          }
        }
#pragma unroll
        for (int rr = 0; rr < 4; rr++)
#pragma unroll
          for (int cc = 0; cc < 4; cc++) {
            float v = acc[rr][cc];
            v += __shfl_xor(v, 1); v += __shfl_xor(v, 2);
            acc[rr][cc] = v;
          }
        float o0 = 0.f, o1 = 0.f, o2 = 0.f, o3 = 0.f;
#pragma unroll
        for (int cc = 0; cc < 4; cc++) {
          o0 = (kg == cc) ? acc[0][cc] : o0;
          o1 = (kg == cc) ? acc[1][cc] : o1;
          o2 = (kg == cc) ? acc[2][cc] : o2;
          o3 = (kg == cc) ? acc[3][cc] : o3;
        }
        float* gr = a.l0 + (size_t)(row0 + ri * 4) * 1024 + nb;
        gr[0]        = o0 + biasv;
        gr[1024]     = o1 + biasv;
        gr[2 * 1024] = o2 + biasv;
        gr[3 * 1024] = o3 + biasv;
      }
    }
  }
  { unsigned* g = a.ctr + 48; bumpF(g); waitcF(g, 512u); }  // grid barrier 2

  //========================= ENCODER LAYER 1 ================================
  // Same paired structure; layer slots 2+dir; gates from G1 (l0 frozen after
  // GB2). Counters REUSED monotonically: E0 left them at 16*T = 2048.
  {
    float* wl  = sm;
    float* hlA = sm + 16512;
    float* hlB = sm + 20640;
    unsigned* cA = a.ctr + dirE * 16 + prE;
    unsigned* cB = a.ctr + dirE * 16 + prE + 8;
    const unsigned base = 16u * T;

    stage16(a.eWhh1 + (size_t)(dirE * H + n0E) * H, wl);
    stage16(a.eWhh1 + (size_t)(dirE * H + n0E + 16) * H, wl + 16 * 516);

    for (int s = 0; s < T; s++) {
      int t_ = dirE ? (T - 1 - s) : s;
      float aA = a.l0[((size_t)t_ * B + (b0A + rlocE)) * 1024 + dirE * H + nlaneE];
      float aB = a.l0[((size_t)t_ * B + (b0B + rlocE)) * 1024 + dirE * H + nlaneE];

      if (s) waitcR(cA, base + 16u * s); else __syncthreads();
      stageC8(a.dst + ((size_t)((s & 1) * 4 + 2 + dirE) * B + b0A) * H, hlA);
      __syncthreads();
      float oA = tanhf(aA + dotK16(hlA + hoffE, wl + woffE, kgE));
      stC(a.dst + ((size_t)(((s + 1) & 1) * 4 + 2 + dirE) * B + (b0A + rlocE)) * H + nlaneE, oA);
      bumpR(cA);

      if (s) waitcR(cB, base + 16u * s);
      stageC8(a.dst + ((size_t)((s & 1) * 4 + 2 + dirE) * B + b0B) * H, hlB);
      __syncthreads();
      float oB = tanhf(aB + dotK16(hlB + hoffE, wl + woffE, kgE));
      stC(a.dst + ((size_t)(((s + 1) & 1) * 4 + 2 + dirE) * B + (b0B + rlocE)) * H + nlaneE, oB);
      bumpR(cB);
    }
  }
  { unsigned* g = a.ctr + 48; bumpF(g); waitcF(g, 768u); }  // grid barrier 3

  //============================== DECODER ===================================
  // ROUND-4 DECODER VERBATIM (passed): block 16b x 16n, 4x4 tile, 16-way split.
  {
    const int btile = bx & 7, ntile = bx >> 3;
    const int b0 = btile * 16, n0 = ntile * 16;
    const int j = tid & 15, bl = tid >> 4;   // mapping for xin/lin sections
    const int kg = tid & 15;                 // lane bits 0..3
    const int ni = (tid >> 4) & 3;           // lane bits 4..5
    const int bi = tid >> 6;                 // wave id, uniform
    float* whh  = sm;           // [16][516]
    float* wir  = sm + 8256;    // [16][516]
    float* hlc  = sm + 16512;   // [16][516] old state of current layer
    float* hin  = sm + 24768;   // [16][516] prev-layer new state (or h3 at l==0)
    float* xinL = sm + 33024;   // [16][4]
    unsigned* c = a.ctr + 32 + btile;

    const int nlane = n0 + ni * 4 + (kg & 3);
    const int rloc  = bi * 4 + (kg >> 2);
    float w00 = a.dWih0[nlane * 3 + 0], w01 = a.dWih0[nlane * 3 + 1], w02 = a.dWih0[nlane * 3 + 2];
    float bias0 = a.dbih[0 * H + nlane] + a.dbhh[0 * H + nlane];
    float bias1 = a.dbih[1 * H + nlane] + a.dbhh[1 * H + nlane];
    float bias2 = a.dbih[2 * H + nlane] + a.dbhh[2 * H + nlane];
    float bias3 = a.dbih[3 * H + nlane] + a.dbhh[3 * H + nlane];

    const float* hp0 = hlc + (bi * 4 + 0) * 516 + kg * 4;
    const float* hp1 = hp0 + 516;
    const float* hp2 = hp0 + 2 * 516;
    const float* hp3 = hp0 + 3 * 516;
    const float* ip0 = hin + (bi * 4 + 0) * 516 + kg * 4;
    const float* ip1 = ip0 + 516;
    const float* ip2 = ip0 + 2 * 516;
    const float* ip3 = ip0 + 3 * 516;
    const float* wp0 = whh + (ni * 4 + 0) * 516 + kg * 4;
    const float* wp1 = wp0 + 516;
    const float* wp2 = wp0 + 2 * 516;
    const float* wp3 = wp0 + 3 * 516;
    const float* up0 = wir + (ni * 4 + 0) * 516 + kg * 4;
    const float* up1 = up0 + 516;
    const float* up2 = up0 + 2 * 516;
    const float* up3 = up0 + 3 * 516;

    // prologue prefetch for m=0 (visible via grid barrier 3's acquire)
    stage16(a.dWhh + (size_t)(0 * H + n0) * H, whh);
    stageC16(a.dst + ((size_t)(0 * 4 + 0) * B + b0) * H, hlc);

    for (int m = 0; m < 128; m++) {
      int s = m >> 2, l = m & 3;
      int p = s & 1, q = 1 - p;
      if (m) waitcR(c, 32u * m); else __syncthreads();

      // only the m-1-produced buffer is staged post-wait
      if (l) {
        stageC16(a.dst + ((size_t)(q * 4 + (l - 1)) * B + b0) * H, hin);
      } else if (s) {
        stageC16(a.dst + ((size_t)(p * 4 + 3) * B + b0) * H, hin);  // h3
      }
      __syncthreads();

      if (l == 0) {
        if (s == 0) {
          if (j == 0) {
            const float* xr = a.x + ((size_t)(b0 + bl) * T + (T - 1)) * 3;
            float v0 = xr[0], v1 = xr[1], v2 = xr[2];
            xinL[bl * 4 + 0] = v0; xinL[bl * 4 + 1] = v1; xinL[bl * 4 + 2] = v2;
            if (ntile == 0) {
              float* xw = a.xing + (size_t)(b0 + bl) * 4;  // parity 0
              stC(xw + 0, v0); stC(xw + 1, v1); stC(xw + 2, v2);
            }
          }
        } else {
          const float* h3r = hin + bl * 516;
          float v = 0.f;
          for (int k = j; k < H; k += 16) v += h3r[k] * a.linW[k];
          v += __shfl_xor(v, 8); v += __shfl_xor(v, 4);
          v += __shfl_xor(v, 2); v += __shfl_xor(v, 1);
          float o0 = v + a.linb[0];
          const float* xp = a.xing + ((size_t)((s - 1) & 1) * B + (b0 + bl)) * 4;
          float sv1 = ldC(xp + 0) - o0;
          float sv2 = ldC(xp + 1) - sv1;
          if (j == 0) {
            xinL[bl * 4 + 0] = o0; xinL[bl * 4 + 1] = sv1; xinL[bl * 4 + 2] = sv2;
            if (ntile == 0) {
              float* xw = a.xing + ((size_t)(s & 1) * B + (b0 + bl)) * 4;
              stC(xw + 0, o0); stC(xw + 1, sv1); stC(xw + 2, sv2);
              a.out[(size_t)(b0 + bl) * TGT + (s - 1)] = o0;
            }
          }
        }
        __syncthreads();
      }

      float acc[4][4];
#pragma unroll
      for (int rr = 0; rr < 4; rr++)
#pragma unroll
        for (int cc = 0; cc < 4; cc++) acc[rr][cc] = 0.f;

      if (l) {
#pragma unroll 2
        for (int i = 0; i < 8; i++) {
          const int k = i * 64;
          float4 h0 = *(const float4*)(hp0 + k);
          float4 h1 = *(const float4*)(hp1 + k);
          float4 h2 = *(const float4*)(hp2 + k);
          float4 h3 = *(const float4*)(hp3 + k);
          float4 i0 = *(const float4*)(ip0 + k);
          float4 i1 = *(const float4*)(ip1 + k);
          float4 i2 = *(const float4*)(ip2 + k);
          float4 i3 = *(const float4*)(ip3 + k);
          float4 w0 = *(const float4*)(wp0 + k);
          float4 w1 = *(const float4*)(wp1 + k);
          float4 w2 = *(const float4*)(wp2 + k);
          float4 w3 = *(const float4*)(wp3 + k);
          float4 u0 = *(const float4*)(up0 + k);
          float4 u1 = *(const float4*)(up1 + k);
          float4 u2 = *(const float4*)(up2 + k);
          float4 u3 = *(const float4*)(up3 + k);
          DOT4B(acc[0][0], h0, w0, i0, u0); DOT4B(acc[0][1], h0, w1, i0, u1);
          DOT4B(acc[0][2], h0, w2, i0, u2); DOT4B(acc[0][3], h0, w3, i0, u3);
          DOT4B(acc[1][0], h1, w0, i1, u0); DOT4B(acc[1][1], h1, w1, i1, u1);
          DOT4B(acc[1][2], h1, w2, i1, u2); DOT4B(acc[1][3], h1, w3, i1, u3);
          DOT4B(acc[2][0], h2, w0, i2, u0); DOT4B(acc[2][1], h2, w1, i2, u1);
          DOT4B(acc[2][2], h2, w2, i2, u2); DOT4B(acc[2][3], h2, w3, i2, u3);
          DOT4B(acc[3][0], h3, w0, i3, u0); DOT4B(acc[3][1], h3, w1, i3, u1);
          DOT4B(acc[3][2], h3, w2, i3, u2); DOT4B(acc[3][3], h3, w3, i3, u3);
        }
      } else {
#pragma unroll 2
        for (int i = 0; i < 8; i++) {
          const int k = i * 64;
          float4 h0 = *(const float4*)(hp0 + k);
          float4 h1 = *(const float4*)(hp1 + k);
          float4 h2 = *(const float4*)(hp2 + k);
          float4 h3 = *(const float4*)(hp3 + k);
          float4 w0 = *(const float4*)(wp0 + k);
          float4 w1 = *(const float4*)(wp1 + k);
          float4 w2 = *(const float4*)(wp2 + k);
          float4 w3 = *(const float4*)(wp3 + k);
          DOT4(acc[0][0], h0, w0); DOT4(acc[0][1], h0, w1); DOT4(acc[0][2], h0, w2); DOT4(acc[0][3], h0, w3);
          DOT4(acc[1][0], h1, w0); DOT4(acc[1][1], h1, w1); DOT4(acc[1][2], h1, w2); DOT4(acc[1][3], h1, w3);
          DOT4(acc[2][0], h2, w0); DOT4(acc[2][1], h2, w1); DOT4(acc[2][2], h2, w2); DOT4(acc[2][3], h2, w3);
          DOT4(acc[3][0], h3, w0); DOT4(acc[3][1], h3, w1); DOT4(acc[3][2], h3, w2); DOT4(acc[3][3], h3, w3);
        }
      }
      // reduce over 16 k-groups (lane bits 0..3)
#pragma unroll
      for (int rr = 0; rr < 4; rr++)
#pragma unroll
        for (int cc = 0; cc < 4; cc++) {
          float v = acc[rr][cc];
          v += __shfl_xor(v, 1); v += __shfl_xor(v, 2);
          v += __shfl_xor(v, 4); v += __shfl_xor(v, 8);
          acc[rr][cc] = v;
        }
      float sv = 0.f;
#pragma unroll
      for (int rr = 0; rr < 4; rr++)
#pragma unroll
        for (int cc = 0; cc < 4; cc++)
          sv = (kg == rr * 4 + cc) ? acc[rr][cc] : sv;

      float bs = (l == 0) ? bias0 : (l == 1) ? bias1 : (l == 2) ? bias2 : bias3;
      float at = bs;
      if (l == 0)
        at += xinL[rloc * 4 + 0] * w00 + xinL[rloc * 4 + 1] * w01 + xinL[rloc * 4 + 2] * w02;
      float hnew = tanhf(at + sv);
      stC(a.dst + ((size_t)(q * 4 + l) * B + (b0 + rloc)) * H + nlane, hnew);
      bumpR(c);

      // prefetch next step's weights + hlc (released >= 1 step ago) while
      // the group barrier for m+1 is still pending
      if (m < 127) {
        int m2 = m + 1, l2 = m2 & 3, s2 = m2 >> 2, p2 = s2 & 1;
        stage16(a.dWhh + (size_t)(l2 * H + n0) * H, whh);
        if (l2)
          stage16(a.dWihr + (size_t)((l2 - 1) * H + n0) * H, wir);
        stageC16(a.dst + ((size_t)(p2 * 4 + l2) * B + b0) * H, hlc);
      }
    }

    if (ntile == 0) {  // final output column t=31 from dstate[0][3]
      waitcR(c, 32u * 128);
      const float* h3g = a.dst + ((size_t)(0 * 4 + 3) * B + (b0 + bl)) * H;
      float v = 0.f;
      for (int k = j; k < H; k += 16) v += ldC(h3g + k) * a.linW[k];
      v += __shfl_xor(v, 8); v += __shfl_xor(v, 4);
      v += __shfl_xor(v, 2); v += __shfl_xor(v, 1);
      if (j == 0) a.out[(size_t)(b0 + bl) * TGT + 31] = v + a.linb[0];
    }
  }
}

#undef DOT4
#undef DOT4B

// ---------------------------------------------------------------------------
extern "C" void kernel_launch(void* const* d_in, const int* in_sizes, int n_in,
                              void* d_out, int out_size, void* d_ws, size_t ws_size,
                              hipStream_t stream) {
  // ws layout (~66.0 MB): dstate 2MB | xing 4KB | ctr 256B | l0/G1 64MB
  float* dst  = (float*)d_ws;
  float* xing = dst + 2 * 4 * B * H;
  unsigned* ctr = (unsigned*)((char*)d_ws + 2101248);
  float* l0 = (float*)((char*)d_ws + 2101504);

  kinit<<<256, 256, 0, stream>>>(dst, ctr);

  Args args;
  args.x     = (const float*)d_in[0];
  args.eWih0 = (const float*)d_in[2];
  args.eWhh0 = (const float*)d_in[3];
  args.eWih1 = (const float*)d_in[4];
  args.eWhh1 = (const float*)d_in[5];
  args.ebih  = (const float*)d_in[6];
  args.ebhh  = (const float*)d_in[7];
  args.dWih0 = (const float*)d_in[8];
  args.dWihr = (const float*)d_in[9];
  args.dWhh  = (const float*)d_in[10];
  args.dbih  = (const float*)d_in[11];
  args.dbhh  = (const float*)d_in[12];
  args.linW  = (const float*)d_in[13];
  args.linb  = (const float*)d_in[14];
  args.dst = dst; args.xing = xing; args.l0 = l0; args.ctr = ctr;
  args.out = (float*)d_out;

  void* kp[] = { &args };
  hipLaunchCooperativeKernel((void*)birnn_all, dim3(256), dim3(256), kp, 0, stream);
}

// Round 9
// 5624.227 us; speedup vs baseline: 1.3982x; 1.3982x over previous
//
#include <hip/hip_runtime.h>
#include <cmath>

#define B 128
#define T 128
#define H 512
#define TGT 32

#define SCOPE_AGENT __HIP_MEMORY_SCOPE_AGENT

struct Args {
  const float *x, *eWih0, *eWhh0, *eWih1, *eWhh1, *ebih, *ebhh;
  const float *dWih0, *dWihr, *dWhh, *dbih, *dbhh, *linW, *linb;
  float *dst;    // dstate [2 parity][4 layer][B][H]  -- agent-scope atomic access ONLY
  float *xing;   // [2][B][4]                          -- agent-scope atomic access ONLY
  float *l0;     // [T][B][1024]  (plain cached; fenced at grid barriers)
  unsigned *ctr; // [64]: 0..31 E (dir*16+btile; E1 reuses monotone), 32..39 DEC, 48 grid
  float *out;    // [B][TGT]
};

// ---------------------------------------------------------------------------
__global__ void kinit(float* __restrict__ st, unsigned* __restrict__ ctr) {
  int idx = blockIdx.x * 256 + threadIdx.x;
  for (int i = idx; i < 4 * B * H; i += 256 * 256) st[i] = 0.f;  // parity-0 state
  if (idx < 64) ctr[idx] = 0u;
}

// --------------------------- sync primitives -------------------------------
__device__ __forceinline__ void bumpR(unsigned* c) {
  __syncthreads();  // all waves' agent-scope stores drained to MALL
  if (threadIdx.x == 0)
    __hip_atomic_fetch_add(c, 1u, __ATOMIC_RELAXED, SCOPE_AGENT);
}
__device__ __forceinline__ void waitcR(unsigned* c, unsigned tgt) {
  if (threadIdx.x == 0)
    while (__hip_atomic_load(c, __ATOMIC_RELAXED, SCOPE_AGENT) < tgt)
      __builtin_amdgcn_s_sleep(2);
  __syncthreads();
}
// grid barriers: full release/acquire (flush/inv L2) for the plain-cached l0/G1
__device__ __forceinline__ void bumpF(unsigned* c) {
  __syncthreads();
  if (threadIdx.x == 0)
    __hip_atomic_fetch_add(c, 1u, __ATOMIC_RELEASE, SCOPE_AGENT);
}
__device__ __forceinline__ void waitcF(unsigned* c, unsigned tgt) {
  if (threadIdx.x == 0) {
    while (__hip_atomic_load(c, __ATOMIC_RELAXED, SCOPE_AGENT) < tgt)
      __builtin_amdgcn_s_sleep(2);
    __builtin_amdgcn_fence(__ATOMIC_ACQUIRE, "agent");
  }
  __syncthreads();
}

// --------------------------- staging helpers -------------------------------
__device__ __forceinline__ void stC(float* p, float v) {
  __hip_atomic_store(p, v, __ATOMIC_RELAXED, SCOPE_AGENT);
}
__device__ __forceinline__ float ldC(const float* p) {
  return __hip_atomic_load(p, __ATOMIC_RELAXED, SCOPE_AGENT);
}

// generic rolled stage (G1 only; not latency-critical)
template <int ROWLEN, int GSTRIDE>
__device__ __forceinline__ void stage(const float* __restrict__ g,
                                      float* __restrict__ l, int rows, int lstride) {
  int total = rows * ROWLEN;
  for (int idx = (int)threadIdx.x * 4; idx < total; idx += 1024) {
    int r = idx / ROWLEN, k = idx - r * ROWLEN;
    float4 v = *(const float4*)(g + (size_t)r * GSTRIDE + k);
    *(float4*)(l + r * lstride + k) = v;
  }
}

// 16 rows x 512 floats, plain cached loads (weights), fully unrolled
__device__ __forceinline__ void stage16(const float* __restrict__ g,
                                        float* __restrict__ l) {
  const int t = threadIdx.x;
  const int r0 = t >> 7, k0 = (t & 127) * 4;
  float4 v[8];
#pragma unroll
  for (int i = 0; i < 8; i++)
    v[i] = *(const float4*)(g + (size_t)(r0 + 2 * i) * 512 + k0);
#pragma unroll
  for (int i = 0; i < 8; i++)
    *(float4*)(l + (r0 + 2 * i) * 516 + k0) = v[i];
}

// 16 rows x 512 floats, DEVICE-COHERENT (8B agent atomics), fully unrolled
__device__ __forceinline__ void stageC16(const float* __restrict__ g,
                                         float* __restrict__ l) {
  const unsigned long long* gu = (const unsigned long long*)g;
  unsigned long long* lu = (unsigned long long*)l;
  const int t = threadIdx.x;
  unsigned long long v[16];
#pragma unroll
  for (int i = 0; i < 16; i++)
    v[i] = __hip_atomic_load(gu + (size_t)i * 256 + t, __ATOMIC_RELAXED, SCOPE_AGENT);
#pragma unroll
  for (int i = 0; i < 16; i++)
    lu[i * 258 + t] = v[i];
}

// 8 rows x 512 floats, DEVICE-COHERENT, fully unrolled
__device__ __forceinline__ void stageC8(const float* __restrict__ g,
                                        float* __restrict__ l) {
  const unsigned long long* gu = (const unsigned long long*)g;
  unsigned long long* lu = (unsigned long long*)l;
  const int t = threadIdx.x;
  unsigned long long v[8];
#pragma unroll
  for (int i = 0; i < 8; i++)
    v[i] = __hip_atomic_load(gu + (size_t)i * 256 + t, __ATOMIC_RELAXED, SCOPE_AGENT);
#pragma unroll
  for (int i = 0; i < 8; i++)
    lu[i * 258 + t] = v[i];
}

#define DOT4(accv, hv, wv) accv += hv.x*wv.x + hv.y*wv.y + hv.z*wv.z + hv.w*wv.w
#define DOT4B(accv, hv, wv, iv, uv)                                       \
  accv += hv.x*wv.x + hv.y*wv.y + hv.z*wv.z + hv.w*wv.w                   \
        + iv.x*uv.x + iv.y*uv.y + iv.z*uv.z + iv.w*uv.w

// ---------------------------------------------------------------------------
__global__ __launch_bounds__(256, 1) void birnn_all(Args a) {
  __shared__ __align__(16) float sm[37152];   // 148608 B, unioned per phase
  const int tid = threadIdx.x;
  const int bx = blockIdx.x;

  // E-phase decomposition (both layers): block (dir=bx>>7, btile=(bx>>3)&15,
  // ntile=bx&7). Single chain per block: 8 batches (btile*8..+7) x 64 n
  // (ntile*64..+63). GROUP = 8 members (one per ntile) -> half the counter
  // fan-in and HALF the redundant h-staging of the round-4 16-member layout.
  // Thread map (round-2-verified two-output pattern): kg=tid&7 (8-way k-split),
  // ni=(tid>>3)&15 (16x4=64 cols), bi=tid>>7 (2x4=8 rows). Lane kg owns
  // outputs (row r1=bi*4+(kg>>2), col nlane) and (row r2=r1+2, col nlane).
  const int dirE = bx >> 7, btE = (bx >> 3) & 15, ntE = bx & 7;
  const int b0E = btE * 8, n0E = ntE * 64;
  const int kgE = tid & 7, niE = (tid >> 3) & 15, biE = tid >> 7;
  const int nlaneE = n0E + niE * 4 + (kgE & 3);
  const int r1E = biE * 4 + (kgE >> 2);
  const int r2E = r1E + 2;
  const int hoffE = biE * 4 * 516 + kgE * 4;
  const int woffE = niE * 4 * 516 + kgE * 4;

  //========================= ENCODER LAYER 0 ================================
  {
    float* wl = sm;          // [64][516] eWhh0[dirE] rows n0E..n0E+63
    float* hl = sm + 33024;  // [8][516]
    unsigned* c = a.ctr + dirE * 16 + btE;

    stage16(a.eWhh0 + (size_t)(dirE * H + n0E) * H, wl);
    stage16(a.eWhh0 + (size_t)(dirE * H + n0E + 16) * H, wl + 16 * 516);
    stage16(a.eWhh0 + (size_t)(dirE * H + n0E + 32) * H, wl + 32 * 516);
    stage16(a.eWhh0 + (size_t)(dirE * H + n0E + 48) * H, wl + 48 * 516);

    float wx0 = a.eWih0[(dirE * H + nlaneE) * 3 + 0];
    float wx1 = a.eWih0[(dirE * H + nlaneE) * 3 + 1];
    float wx2 = a.eWih0[(dirE * H + nlaneE) * 3 + 2];
    float bias = a.ebih[dirE * H + nlaneE] + a.ebhh[dirE * H + nlaneE];

    const float* hp0 = hl + hoffE;
    const float* hp1 = hp0 + 516;
    const float* hp2 = hp0 + 2 * 516;
    const float* hp3 = hp0 + 3 * 516;
    const float* wp0 = wl + woffE;
    const float* wp1 = wp0 + 516;
    const float* wp2 = wp0 + 2 * 516;
    const float* wp3 = wp0 + 3 * 516;

    for (int s = 0; s < T; s++) {
      int t_ = dirE ? (T - 1 - s) : s;
      const float* xr1 = a.x + ((size_t)(b0E + r1E) * T + t_) * 3;
      const float* xr2 = a.x + ((size_t)(b0E + r2E) * T + t_) * 3;
      float a1 = bias + xr1[0] * wx0 + xr1[1] * wx1 + xr1[2] * wx2;
      float a2 = bias + xr2[0] * wx0 + xr2[1] * wx1 + xr2[2] * wx2;

      if (s) waitcR(c, 8u * s); else __syncthreads();
      stageC8(a.dst + ((size_t)((s & 1) * 4 + dirE) * B + b0E) * H, hl);
      __syncthreads();

      float acc[4][4];
#pragma unroll
      for (int rr = 0; rr < 4; rr++)
#pragma unroll
        for (int cc = 0; cc < 4; cc++) acc[rr][cc] = 0.f;

#pragma unroll 4
      for (int i = 0; i < 16; i++) {
        const int k = i * 32;   // 8 kg * 4 floats = 32 per iter, 16 iters = 512
        float4 h0 = *(const float4*)(hp0 + k);
        float4 h1 = *(const float4*)(hp1 + k);
        float4 h2 = *(const float4*)(hp2 + k);
        float4 h3 = *(const float4*)(hp3 + k);
        float4 w0 = *(const float4*)(wp0 + k);
        float4 w1 = *(const float4*)(wp1 + k);
        float4 w2 = *(const float4*)(wp2 + k);
        float4 w3 = *(const float4*)(wp3 + k);
        DOT4(acc[0][0],h0,w0); DOT4(acc[0][1],h0,w1); DOT4(acc[0][2],h0,w2); DOT4(acc[0][3],h0,w3);
        DOT4(acc[1][0],h1,w0); DOT4(acc[1][1],h1,w1); DOT4(acc[1][2],h1,w2); DOT4(acc[1][3],h1,w3);
        DOT4(acc[2][0],h2,w0); DOT4(acc[2][1],h2,w1); DOT4(acc[2][2],h2,w2); DOT4(acc[2][3],h2,w3);
        DOT4(acc[3][0],h3,w0); DOT4(acc[3][1],h3,w1); DOT4(acc[3][2],h3,w2); DOT4(acc[3][3],h3,w3);
      }
      // reduce over 8 k-groups (lane bits 0..2)
#pragma unroll
      for (int rr = 0; rr < 4; rr++)
#pragma unroll
        for (int cc = 0; cc < 4; cc++) {
          float v = acc[rr][cc];
          v += __shfl_xor(v, 1); v += __shfl_xor(v, 2); v += __shfl_xor(v, 4);
          acc[rr][cc] = v;
        }
      float s0v = 0.f, s1v = 0.f;
#pragma unroll
      for (int rr = 0; rr < 2; rr++)
#pragma unroll
        for (int cc = 0; cc < 4; cc++) {
          s0v = (kgE == rr * 4 + cc) ? acc[rr][cc] : s0v;
          s1v = (kgE == rr * 4 + cc) ? acc[rr + 2][cc] : s1v;
        }
      float o1 = tanhf(a1 + s0v);
      float o2 = tanhf(a2 + s1v);
      float* hw = a.dst + (size_t)(((s + 1) & 1) * 4 + dirE) * B * H;
      stC(hw + (size_t)(b0E + r1E) * H + nlaneE, o1);
      stC(hw + (size_t)(b0E + r2E) * H + nlaneE, o2);
      bumpR(c);
      // l0 only consumed after grid barrier 1 (fenced) -> plain stores, deferred
      a.l0[((size_t)t_ * B + (b0E + r1E)) * 1024 + dirE * H + nlaneE] = o1;
      a.l0[((size_t)t_ * B + (b0E + r2E)) * 1024 + dirE * H + nlaneE] = o2;
    }
  }
  { unsigned* g = a.ctr + 48; bumpF(g); waitcF(g, 256u); }  // grid barrier 1

  //===================== ENC1 INPUT PROJECTION (in-place G1) ================
  {
    float* xl = sm;          // [16][1028]
    float* wl = sm + 16448;  // [64][260]
    const int kg = tid & 3;
    const int ci = (tid >> 2) & 15;
    const int ri = tid >> 6;
    for (int rt = 0; rt < 4; rt++) {
      int row0 = (bx * 4 + rt) * 16;
      __syncthreads();
      stage<1024, 1024>(a.l0 + (size_t)row0 * 1024, xl, 16, 1028);
      __syncthreads();
      for (int nc = 0; nc < 16; nc++) {
        const int nb = nc * 64 + ci * 4 + kg;
        float biasv = a.ebih[(2 + (nb >> 9)) * H + (nb & 511)] +
                      a.ebhh[(2 + (nb >> 9)) * H + (nb & 511)];
        float acc[4][4];
#pragma unroll
        for (int rr = 0; rr < 4; rr++)
#pragma unroll
          for (int cc = 0; cc < 4; cc++) acc[rr][cc] = 0.f;

        for (int kp = 0; kp < 4; kp++) {
          __syncthreads();
          stage<256, 1024>(a.eWih1 + (size_t)(nc * 64) * 1024 + kp * 256, wl, 64, 260);
          __syncthreads();
          const float* xp0 = xl + (ri * 4 + 0) * 1028 + kp * 256 + kg * 4;
          const float* xp1 = xp0 + 1028;
          const float* xp2 = xp0 + 2 * 1028;
          const float* xp3 = xp0 + 3 * 1028;
          const float* wq0 = wl + (ci * 4 + 0) * 260 + kg * 4;
          const float* wq1 = wq0 + 260;
          const float* wq2 = wq0 + 2 * 260;
          const float* wq3 = wq0 + 3 * 260;
#pragma unroll 4
          for (int i = 0; i < 16; i++) {
            const int k = i * 16;
            float4 x0 = *(const float4*)(xp0 + k);
            float4 x1 = *(const float4*)(xp1 + k);
            float4 x2 = *(const float4*)(xp2 + k);
            float4 x3 = *(const float4*)(xp3 + k);
            float4 w0 = *(const float4*)(wq0 + k);
            float4 w1 = *(const float4*)(wq1 + k);
            float4 w2 = *(const float4*)(wq2 + k);
            float4 w3 = *(const float4*)(wq3 + k);
            DOT4(acc[0][0], x0, w0); DOT4(acc[0][1], x0, w1); DOT4(acc[0][2], x0, w2); DOT4(acc[0][3], x0, w3);
            DOT4(acc[1][0], x1, w0); DOT4(acc[1][1], x1, w1); DOT4(acc[1][2], x1, w2); DOT4(acc[1][3], x1, w3);
            DOT4(acc[2][0], x2, w0); DOT4(acc[2][1], x2, w1); DOT4(acc[2][2], x2, w2); DOT4(acc[2][3], x2, w3);
            DOT4(acc[3][0], x3, w0); DOT4(acc[3][1], x3, w1); DOT4(acc[3][2], x3, w2); DOT4(acc[3][3], x3, w3);
          }
        }
#pragma unroll
        for (int rr = 0; rr < 4; rr++)
#pragma unroll
          for (int cc = 0; cc < 4; cc++) {
            float v = acc[rr][cc];
            v += __shfl_xor(v, 1); v += __shfl_xor(v, 2);
            acc[rr][cc] = v;
          }
        float o0 = 0.f, o1 = 0.f, o2 = 0.f, o3 = 0.f;
#pragma unroll
        for (int cc = 0; cc < 4; cc++) {
          o0 = (kg == cc) ? acc[0][cc] : o0;
          o1 = (kg == cc) ? acc[1][cc] : o1;
          o2 = (kg == cc) ? acc[2][cc] : o2;
          o3 = (kg == cc) ? acc[3][cc] : o3;
        }
        float* gr = a.l0 + (size_t)(row0 + ri * 4) * 1024 + nb;
        gr[0]        = o0 + biasv;
        gr[1024]     = o1 + biasv;
        gr[2 * 1024] = o2 + biasv;
        gr[3 * 1024] = o3 + biasv;
      }
    }
  }
  { unsigned* g = a.ctr + 48; bumpF(g); waitcF(g, 512u); }  // grid barrier 2

  //========================= ENCODER LAYER 1 ================================
  // Same 8-member layout; layer slots 2+dir; gates from G1 (l0 frozen after
  // GB2). Counters REUSED monotonically: E0 left them at 8*T = 1024.
  {
    float* wl = sm;
    float* hl = sm + 33024;
    unsigned* c = a.ctr + dirE * 16 + btE;
    const unsigned base = 8u * T;

    stage16(a.eWhh1 + (size_t)(dirE * H + n0E) * H, wl);
    stage16(a.eWhh1 + (size_t)(dirE * H + n0E + 16) * H, wl + 16 * 516);
    stage16(a.eWhh1 + (size_t)(dirE * H + n0E + 32) * H, wl + 32 * 516);
    stage16(a.eWhh1 + (size_t)(dirE * H + n0E + 48) * H, wl + 48 * 516);

    const float* hp0 = hl + hoffE;
    const float* hp1 = hp0 + 516;
    const float* hp2 = hp0 + 2 * 516;
    const float* hp3 = hp0 + 3 * 516;
    const float* wp0 = wl + woffE;
    const float* wp1 = wp0 + 516;
    const float* wp2 = wp0 + 2 * 516;
    const float* wp3 = wp0 + 3 * 516;

    for (int s = 0; s < T; s++) {
      int t_ = dirE ? (T - 1 - s) : s;
      float a1 = a.l0[((size_t)t_ * B + (b0E + r1E)) * 1024 + dirE * H + nlaneE];
      float a2 = a.l0[((size_t)t_ * B + (b0E + r2E)) * 1024 + dirE * H + nlaneE];

      if (s) waitcR(c, base + 8u * s); else __syncthreads();
      stageC8(a.dst + ((size_t)((s & 1) * 4 + 2 + dirE) * B + b0E) * H, hl);
      __syncthreads();

      float acc[4][4];
#pragma unroll
      for (int rr = 0; rr < 4; rr++)
#pragma unroll
        for (int cc = 0; cc < 4; cc++) acc[rr][cc] = 0.f;

#pragma unroll 4
      for (int i = 0; i < 16; i++) {
        const int k = i * 32;
        float4 h0 = *(const float4*)(hp0 + k);
        float4 h1 = *(const float4*)(hp1 + k);
        float4 h2 = *(const float4*)(hp2 + k);
        float4 h3 = *(const float4*)(hp3 + k);
        float4 w0 = *(const float4*)(wp0 + k);
        float4 w1 = *(const float4*)(wp1 + k);
        float4 w2 = *(const float4*)(wp2 + k);
        float4 w3 = *(const float4*)(wp3 + k);
        DOT4(acc[0][0],h0,w0); DOT4(acc[0][1],h0,w1); DOT4(acc[0][2],h0,w2); DOT4(acc[0][3],h0,w3);
        DOT4(acc[1][0],h1,w0); DOT4(acc[1][1],h1,w1); DOT4(acc[1][2],h1,w2); DOT4(acc[1][3],h1,w3);
        DOT4(acc[2][0],h2,w0); DOT4(acc[2][1],h2,w1); DOT4(acc[2][2],h2,w2); DOT4(acc[2][3],h2,w3);
        DOT4(acc[3][0],h3,w0); DOT4(acc[3][1],h3,w1); DOT4(acc[3][2],h3,w2); DOT4(acc[3][3],h3,w3);
      }
#pragma unroll
      for (int rr = 0; rr < 4; rr++)
#pragma unroll
        for (int cc = 0; cc < 4; cc++) {
          float v = acc[rr][cc];
          v += __shfl_xor(v, 1); v += __shfl_xor(v, 2); v += __shfl_xor(v, 4);
          acc[rr][cc] = v;
        }
      float s0v = 0.f, s1v = 0.f;
#pragma unroll
      for (int rr = 0; rr < 2; rr++)
#pragma unroll
        for (int cc = 0; cc < 4; cc++) {
          s0v = (kgE == rr * 4 + cc) ? acc[rr][cc] : s0v;
          s1v = (kgE == rr * 4 + cc) ? acc[rr + 2][cc] : s1v;
        }
      float o1 = tanhf(a1 + s0v);
      float o2 = tanhf(a2 + s1v);
      float* hw = a.dst + (size_t)(((s + 1) & 1) * 4 + 2 + dirE) * B * H;
      stC(hw + (size_t)(b0E + r1E) * H + nlaneE, o1);
      stC(hw + (size_t)(b0E + r2E) * H + nlaneE, o2);
      bumpR(c);
    }
  }
  { unsigned* g = a.ctr + 48; bumpF(g); waitcF(g, 768u); }  // grid barrier 3

  //============================== DECODER ===================================
  // ROUND-4 DECODER VERBATIM (passed 3x): block 16b x 16n, 4x4 tile, 16-way.
  {
    const int btile = bx & 7, ntile = bx >> 3;
    const int b0 = btile * 16, n0 = ntile * 16;
    const int j = tid & 15, bl = tid >> 4;   // mapping for xin/lin sections
    const int kg = tid & 15;                 // lane bits 0..3
    const int ni = (tid >> 4) & 3;           // lane bits 4..5
    const int bi = tid >> 6;                 // wave id, uniform
    float* whh  = sm;           // [16][516]
    float* wir  = sm + 8256;    // [16][516]
    float* hlc  = sm + 16512;   // [16][516] old state of current layer
    float* hin  = sm + 24768;   // [16][516] prev-layer new state (or h3 at l==0)
    float* xinL = sm + 33024;   // [16][4]
    unsigned* c = a.ctr + 32 + btile;

    const int nlane = n0 + ni * 4 + (kg & 3);
    const int rloc  = bi * 4 + (kg >> 2);
    float w00 = a.dWih0[nlane * 3 + 0], w01 = a.dWih0[nlane * 3 + 1], w02 = a.dWih0[nlane * 3 + 2];
    float bias0 = a.dbih[0 * H + nlane] + a.dbhh[0 * H + nlane];
    float bias1 = a.dbih[1 * H + nlane] + a.dbhh[1 * H + nlane];
    float bias2 = a.dbih[2 * H + nlane] + a.dbhh[2 * H + nlane];
    float bias3 = a.dbih[3 * H + nlane] + a.dbhh[3 * H + nlane];

    const float* hp0 = hlc + (bi * 4 + 0) * 516 + kg * 4;
    const float* hp1 = hp0 + 516;
    const float* hp2 = hp0 + 2 * 516;
    const float* hp3 = hp0 + 3 * 516;
    const float* ip0 = hin + (bi * 4 + 0) * 516 + kg * 4;
    const float* ip1 = ip0 + 516;
    const float* ip2 = ip0 + 2 * 516;
    const float* ip3 = ip0 + 3 * 516;
    const float* wp0 = whh + (ni * 4 + 0) * 516 + kg * 4;
    const float* wp1 = wp0 + 516;
    const float* wp2 = wp0 + 2 * 516;
    const float* wp3 = wp0 + 3 * 516;
    const float* up0 = wir + (ni * 4 + 0) * 516 + kg * 4;
    const float* up1 = up0 + 516;
    const float* up2 = up0 + 2 * 516;
    const float* up3 = up0 + 3 * 516;

    // prologue prefetch for m=0 (visible via grid barrier 3's acquire)
    stage16(a.dWhh + (size_t)(0 * H + n0) * H, whh);
    stageC16(a.dst + ((size_t)(0 * 4 + 0) * B + b0) * H, hlc);

    for (int m = 0; m < 128; m++) {
      int s = m >> 2, l = m & 3;
      int p = s & 1, q = 1 - p;
      if (m) waitcR(c, 32u * m); else __syncthreads();

      // only the m-1-produced buffer is staged post-wait
      if (l) {
        stageC16(a.dst + ((size_t)(q * 4 + (l - 1)) * B + b0) * H, hin);
      } else if (s) {
        stageC16(a.dst + ((size_t)(p * 4 + 3) * B + b0) * H, hin);  // h3
      }
      __syncthreads();

      if (l == 0) {
        if (s == 0) {
          if (j == 0) {
            const float* xr = a.x + ((size_t)(b0 + bl) * T + (T - 1)) * 3;
            float v0 = xr[0], v1 = xr[1], v2 = xr[2];
            xinL[bl * 4 + 0] = v0; xinL[bl * 4 + 1] = v1; xinL[bl * 4 + 2] = v2;
            if (ntile == 0) {
              float* xw = a.xing + (size_t)(b0 + bl) * 4;  // parity 0
              stC(xw + 0, v0); stC(xw + 1, v1); stC(xw + 2, v2);
            }
          }
        } else {
          const float* h3r = hin + bl * 516;
          float v = 0.f;
          for (int k = j; k < H; k += 16) v += h3r[k] * a.linW[k];
          v += __shfl_xor(v, 8); v += __shfl_xor(v, 4);
          v += __shfl_xor(v, 2); v += __shfl_xor(v, 1);
          float o0 = v + a.linb[0];
          const float* xp = a.xing + ((size_t)((s - 1) & 1) * B + (b0 + bl)) * 4;
          float sv1 = ldC(xp + 0) - o0;
          float sv2 = ldC(xp + 1) - sv1;
          if (j == 0) {
            xinL[bl * 4 + 0] = o0; xinL[bl * 4 + 1] = sv1; xinL[bl * 4 + 2] = sv2;
            if (ntile == 0) {
              float* xw = a.xing + ((size_t)(s & 1) * B + (b0 + bl)) * 4;
              stC(xw + 0, o0); stC(xw + 1, sv1); stC(xw + 2, sv2);
              a.out[(size_t)(b0 + bl) * TGT + (s - 1)] = o0;
            }
          }
        }
        __syncthreads();
      }

      float acc[4][4];
#pragma unroll
      for (int rr = 0; rr < 4; rr++)
#pragma unroll
        for (int cc = 0; cc < 4; cc++) acc[rr][cc] = 0.f;

      if (l) {
#pragma unroll 2
        for (int i = 0; i < 8; i++) {
          const int k = i * 64;
          float4 h0 = *(const float4*)(hp0 + k);
          float4 h1 = *(const float4*)(hp1 + k);
          float4 h2 = *(const float4*)(hp2 + k);
          float4 h3 = *(const float4*)(hp3 + k);
          float4 i0 = *(const float4*)(ip0 + k);
          float4 i1 = *(const float4*)(ip1 + k);
          float4 i2 = *(const float4*)(ip2 + k);
          float4 i3 = *(const float4*)(ip3 + k);
          float4 w0 = *(const float4*)(wp0 + k);
          float4 w1 = *(const float4*)(wp1 + k);
          float4 w2 = *(const float4*)(wp2 + k);
          float4 w3 = *(const float4*)(wp3 + k);
          float4 u0 = *(const float4*)(up0 + k);
          float4 u1 = *(const float4*)(up1 + k);
          float4 u2 = *(const float4*)(up2 + k);
          float4 u3 = *(const float4*)(up3 + k);
          DOT4B(acc[0][0], h0, w0, i0, u0); DOT4B(acc[0][1], h0, w1, i0, u1);
          DOT4B(acc[0][2], h0, w2, i0, u2); DOT4B(acc[0][3], h0, w3, i0, u3);
          DOT4B(acc[1][0], h1, w0, i1, u0); DOT4B(acc[1][1], h1, w1, i1, u1);
          DOT4B(acc[1][2], h1, w2, i1, u2); DOT4B(acc[1][3], h1, w3, i1, u3);
          DOT4B(acc[2][0], h2, w0, i2, u0); DOT4B(acc[2][1], h2, w1, i2, u1);
          DOT4B(acc[2][2], h2, w2, i2, u2); DOT4B(acc[2][3], h2, w3, i2, u3);
          DOT4B(acc[3][0], h3, w0, i3, u0); DOT4B(acc[3][1], h3, w1, i3, u1);
          DOT4B(acc[3][2], h3, w2, i3, u2); DOT4B(acc[3][3], h3, w3, i3, u3);
        }
      } else {
#pragma unroll 2
        for (int i = 0; i < 8; i++) {
          const int k = i * 64;
          float4 h0 = *(const float4*)(hp0 + k);
          float4 h1 = *(const float4*)(hp1 + k);
          float4 h2 = *(const float4*)(hp2 + k);
          float4 h3 = *(const float4*)(hp3 + k);
          float4 w0 = *(const float4*)(wp0 + k);
          float4 w1 = *(const float4*)(wp1 + k);
          float4 w2 = *(const float4*)(wp2 + k);
          float4 w3 = *(const float4*)(wp3 + k);
          DOT4(acc[0][0], h0, w0); DOT4(acc[0][1], h0, w1); DOT4(acc[0][2], h0, w2); DOT4(acc[0][3], h0, w3);
          DOT4(acc[1][0], h1, w0); DOT4(acc[1][1], h1, w1); DOT4(acc[1][2], h1, w2); DOT4(acc[1][3], h1, w3);
          DOT4(acc[2][0], h2, w0); DOT4(acc[2][1], h2, w1); DOT4(acc[2][2], h2, w2); DOT4(acc[2][3], h2, w3);
          DOT4(acc[3][0], h3, w0); DOT4(acc[3][1], h3, w1); DOT4(acc[3][2], h3, w2); DOT4(acc[3][3], h3, w3);
        }
      }
      // reduce over 16 k-groups (lane bits 0..3)
#pragma unroll
      for (int rr = 0; rr < 4; rr++)
#pragma unroll
        for (int cc = 0; cc < 4; cc++) {
          float v = acc[rr][cc];
          v += __shfl_xor(v, 1); v += __shfl_xor(v, 2);
          v += __shfl_xor(v, 4); v += __shfl_xor(v, 8);
          acc[rr][cc] = v;
        }
      float sv = 0.f;
#pragma unroll
      for (int rr = 0; rr < 4; rr++)
#pragma unroll
        for (int cc = 0; cc < 4; cc++)
          sv = (kg == rr * 4 + cc) ? acc[rr][cc] : sv;

      float bs = (l == 0) ? bias0 : (l == 1) ? bias1 : (l == 2) ? bias2 : bias3;
      float at = bs;
      if (l == 0)
        at += xinL[rloc * 4 + 0] * w00 + xinL[rloc * 4 + 1] * w01 + xinL[rloc * 4 + 2] * w02;
      float hnew = tanhf(at + sv);
      stC(a.dst + ((size_t)(q * 4 + l) * B + (b0 + rloc)) * H + nlane, hnew);
      bumpR(c);

      // prefetch next step's weights + hlc (released >= 1 step ago) while
      // the group barrier for m+1 is still pending
      if (m < 127) {
        int m2 = m + 1, l2 = m2 & 3, s2 = m2 >> 2, p2 = s2 & 1;
        stage16(a.dWhh + (size_t)(l2 * H + n0) * H, whh);
        if (l2)
          stage16(a.dWihr + (size_t)((l2 - 1) * H + n0) * H, wir);
        stageC16(a.dst + ((size_t)(p2 * 4 + l2) * B + b0) * H, hlc);
      }
    }

    if (ntile == 0) {  // final output column t=31 from dstate[0][3]
      waitcR(c, 32u * 128);
      const float* h3g = a.dst + ((size_t)(0 * 4 + 3) * B + (b0 + bl)) * H;
      float v = 0.f;
      for (int k = j; k < H; k += 16) v += ldC(h3g + k) * a.linW[k];
      v += __shfl_xor(v, 8); v += __shfl_xor(v, 4);
      v += __shfl_xor(v, 2); v += __shfl_xor(v, 1);
      if (j == 0) a.out[(size_t)(b0 + bl) * TGT + 31] = v + a.linb[0];
    }
  }
}

#undef DOT4
#undef DOT4B

// ---------------------------------------------------------------------------
extern "C" void kernel_launch(void* const* d_in, const int* in_sizes, int n_in,
                              void* d_out, int out_size, void* d_ws, size_t ws_size,
                              hipStream_t stream) {
  // ws layout (~66.0 MB): dstate 2MB | xing 4KB | ctr 256B | l0/G1 64MB
  float* dst  = (float*)d_ws;
  float* xing = dst + 2 * 4 * B * H;
  unsigned* ctr = (unsigned*)((char*)d_ws + 2101248);
  float* l0 = (float*)((char*)d_ws + 2101504);

  kinit<<<256, 256, 0, stream>>>(dst, ctr);

  Args args;
  args.x     = (const float*)d_in[0];
  args.eWih0 = (const float*)d_in[2];
  args.eWhh0 = (const float*)d_in[3];
  args.eWih1 = (const float*)d_in[4];
  args.eWhh1 = (const float*)d_in[5];
  args.ebih  = (const float*)d_in[6];
  args.ebhh  = (const float*)d_in[7];
  args.dWih0 = (const float*)d_in[8];
  args.dWihr = (const float*)d_in[9];
  args.dWhh  = (const float*)d_in[10];
  args.dbih  = (const float*)d_in[11];
  args.dbhh  = (const float*)d_in[12];
  args.linW  = (const float*)d_in[13];
  args.linb  = (const float*)d_in[14];
  args.dst = dst; args.xing = xing; args.l0 = l0; args.ctr = ctr;
  args.out = (float*)d_out;

  void* kp[] = { &args };
  hipLaunchCooperativeKernel((void*)birnn_all, dim3(256), dim3(256), kp, 0, stream);
}

// Round 10
// 4668.000 us; speedup vs baseline: 1.6846x; 1.2048x over previous
//
#include <hip/hip_runtime.h>
#include <cmath>

#define B 128
#define T 128
#define H 512
#define TGT 32

#define SCOPE_AGENT __HIP_MEMORY_SCOPE_AGENT

struct Args {
  const float *x, *eWih0, *eWhh0, *eWih1, *eWhh1, *ebih, *ebhh;
  const float *dWih0, *dWihr, *dWhh, *dbih, *dbhh, *linW, *linb;
  float *dst;    // dstate [2 parity][4 layer][B][H]  -- agent-scope atomic access ONLY
  float *xing;   // [2][B][4]; elem 3 of each quad = per-producer sync flag (256 slots)
  float *l0;     // [T][B][1024]  (plain cached; fenced at grid barriers)
  unsigned *ctr; // grid barrier counter at [40]
  float *out;    // [B][TGT]
};

// ---------------------------------------------------------------------------
__global__ void kinit(float* __restrict__ st, unsigned* __restrict__ ctr) {
  int idx = blockIdx.x * 256 + threadIdx.x;
  for (int i = idx; i < 4 * B * H; i += 256 * 256) st[i] = 0.f;  // parity-0 state
  if (idx < 64) ctr[idx] = 0u;
  // zero the 256 per-producer flags living at xing quad element 3
  if (idx < 256) ((unsigned*)(st + (size_t)2 * 4 * B * H))[idx * 4 + 3] = 0u;
}

// --------------------------- sync primitives -------------------------------
// Per-producer flag release: one relaxed agent STORE (no RMW -> no MALL
// serialization across group members). __syncthreads drains this block's
// agent-scope data stores first (validated rounds 4-9).
__device__ __forceinline__ void relF(unsigned* U, int slot, unsigned val) {
  __syncthreads();
  if (threadIdx.x == 0)
    __hip_atomic_store(U + 4 * slot + 3, val, __ATOMIC_RELAXED, SCOPE_AGENT);
}
// Wait until min over NP group flags >= tgt. NP independent loads pipeline
// into ~1 round trip per poll.
template <int NP>
__device__ __forceinline__ void waitF(unsigned* U, int slot0, unsigned tgt) {
  if (threadIdx.x == 0) {
    for (;;) {
      unsigned mn = 0xffffffffu;
#pragma unroll
      for (int p = 0; p < NP; p++) {
        unsigned v = __hip_atomic_load(U + 4 * (slot0 + p) + 3,
                                       __ATOMIC_RELAXED, SCOPE_AGENT);
        mn = v < mn ? v : mn;
      }
      if (mn >= tgt) break;
      __builtin_amdgcn_s_sleep(2);
    }
  }
  __syncthreads();
}
// grid barriers: full release/acquire (flush/inv L2) for the plain-cached l0/G1
__device__ __forceinline__ void bumpF(unsigned* c) {
  __syncthreads();
  if (threadIdx.x == 0)
    __hip_atomic_fetch_add(c, 1u, __ATOMIC_RELEASE, SCOPE_AGENT);
}
__device__ __forceinline__ void waitcF(unsigned* c, unsigned tgt) {
  if (threadIdx.x == 0) {
    while (__hip_atomic_load(c, __ATOMIC_RELAXED, SCOPE_AGENT) < tgt)
      __builtin_amdgcn_s_sleep(2);
    __builtin_amdgcn_fence(__ATOMIC_ACQUIRE, "agent");
  }
  __syncthreads();
}

// --------------------------- staging helpers -------------------------------
__device__ __forceinline__ void stC(float* p, float v) {
  __hip_atomic_store(p, v, __ATOMIC_RELAXED, SCOPE_AGENT);
}
__device__ __forceinline__ float ldC(const float* p) {
  return __hip_atomic_load(p, __ATOMIC_RELAXED, SCOPE_AGENT);
}

// generic rolled stage (G1 only; not latency-critical)
template <int ROWLEN, int GSTRIDE>
__device__ __forceinline__ void stage(const float* __restrict__ g,
                                      float* __restrict__ l, int rows, int lstride) {
  int total = rows * ROWLEN;
  for (int idx = (int)threadIdx.x * 4; idx < total; idx += 1024) {
    int r = idx / ROWLEN, k = idx - r * ROWLEN;
    float4 v = *(const float4*)(g + (size_t)r * GSTRIDE + k);
    *(float4*)(l + r * lstride + k) = v;
  }
}

// 16 rows x 512 floats, plain cached loads (weights), fully unrolled
__device__ __forceinline__ void stage16(const float* __restrict__ g,
                                        float* __restrict__ l) {
  const int t = threadIdx.x;
  const int r0 = t >> 7, k0 = (t & 127) * 4;
  float4 v[8];
#pragma unroll
  for (int i = 0; i < 8; i++)
    v[i] = *(const float4*)(g + (size_t)(r0 + 2 * i) * 512 + k0);
#pragma unroll
  for (int i = 0; i < 8; i++)
    *(float4*)(l + (r0 + 2 * i) * 516 + k0) = v[i];
}

// 16 rows x 512 floats, DEVICE-COHERENT (8B agent atomics), fully unrolled
__device__ __forceinline__ void stageC16(const float* __restrict__ g,
                                         float* __restrict__ l) {
  const unsigned long long* gu = (const unsigned long long*)g;
  unsigned long long* lu = (unsigned long long*)l;
  const int t = threadIdx.x;
  unsigned long long v[16];
#pragma unroll
  for (int i = 0; i < 16; i++)
    v[i] = __hip_atomic_load(gu + (size_t)i * 256 + t, __ATOMIC_RELAXED, SCOPE_AGENT);
#pragma unroll
  for (int i = 0; i < 16; i++)
    lu[i * 258 + t] = v[i];
}

#define DOT4(accv, hv, wv) accv += hv.x*wv.x + hv.y*wv.y + hv.z*wv.z + hv.w*wv.w
#define DOT4B(accv, hv, wv, iv, uv)                                       \
  accv += hv.x*wv.x + hv.y*wv.y + hv.z*wv.z + hv.w*wv.w                   \
        + iv.x*uv.x + iv.y*uv.y + iv.z*uv.z + iv.w*uv.w

// ---------------------------------------------------------------------------
__global__ __launch_bounds__(256, 1) void birnn_all(Args a) {
  __shared__ __align__(16) float sm[33088];   // 132352 B, unioned per phase
  const int tid = threadIdx.x;
  const int bx = blockIdx.x;
  unsigned* U = (unsigned*)a.xing;   // flag base

  //========================= ENCODER LAYER 0 ================================
  // ROUND-4 STRUCTURE VERBATIM: block 16b x 32n, 4x4 thread tile, 8-way
  // k-split. Group (dir,btile) = 16 members (ntile). Sync via per-producer
  // flags: slot = (dir*8+btile)*16 + ntile; E0 sets s+1 (1..128).
  {
    const int grp = bx & 15, mem = bx >> 4;
    const int dir = grp >> 3, btile = grp & 7, ntile = mem;
    const int b0 = btile * 16, n0 = ntile * 32;
    const int kg = tid & 7;            // lane bits 0..2
    const int ni = (tid >> 3) & 7;     // lane bits 3..5
    const int bi = tid >> 6;           // wave id 0..3 (uniform per wave)
    float* wl = sm;          // [32][516]
    float* hl = sm + 16512;  // [16][516]
    const int g16 = (dir * 8 + btile) * 16;

    stage16(a.eWhh0 + (size_t)(dir * H + n0) * H, wl);
    stage16(a.eWhh0 + (size_t)(dir * H + n0 + 16) * H, wl + 16 * 516);

    const int nlane = n0 + ni * 4 + (kg & 3);
    const int r1 = bi * 4 + (kg >> 2);
    const int r2 = r1 + 2;
    float wx0 = a.eWih0[(dir * H + nlane) * 3 + 0];
    float wx1 = a.eWih0[(dir * H + nlane) * 3 + 1];
    float wx2 = a.eWih0[(dir * H + nlane) * 3 + 2];
    float bias = a.ebih[dir * H + nlane] + a.ebhh[dir * H + nlane];

    const float* hp0 = hl + (bi * 4 + 0) * 516 + kg * 4;
    const float* hp1 = hp0 + 516;
    const float* hp2 = hp0 + 2 * 516;
    const float* hp3 = hp0 + 3 * 516;
    const float* wp0 = wl + (ni * 4 + 0) * 516 + kg * 4;
    const float* wp1 = wp0 + 516;
    const float* wp2 = wp0 + 2 * 516;
    const float* wp3 = wp0 + 3 * 516;

    for (int s = 0; s < T; s++) {
      int t = dir ? (T - 1 - s) : s;
      // prefetch gate values (x is immutable input) BEFORE the wait
      const float* xr1 = a.x + ((size_t)(b0 + r1) * T + t) * 3;
      const float* xr2 = a.x + ((size_t)(b0 + r2) * T + t) * 3;
      float a1 = bias + xr1[0] * wx0 + xr1[1] * wx1 + xr1[2] * wx2;
      float a2 = bias + xr2[0] * wx0 + xr2[1] * wx1 + xr2[2] * wx2;

      if (s) waitF<16>(U, g16, (unsigned)s); else __syncthreads();
      stageC16(a.dst + ((size_t)((s & 1) * 4 + dir) * B + b0) * H, hl);
      __syncthreads();

      float acc[4][4];
#pragma unroll
      for (int rr = 0; rr < 4; rr++)
#pragma unroll
        for (int cc = 0; cc < 4; cc++) acc[rr][cc] = 0.f;

#pragma unroll 4
      for (int i = 0; i < 16; i++) {
        const int k = i * 32;
        float4 h0 = *(const float4*)(hp0 + k);
        float4 h1 = *(const float4*)(hp1 + k);
        float4 h2 = *(const float4*)(hp2 + k);
        float4 h3 = *(const float4*)(hp3 + k);
        float4 w0 = *(const float4*)(wp0 + k);
        float4 w1 = *(const float4*)(wp1 + k);
        float4 w2 = *(const float4*)(wp2 + k);
        float4 w3 = *(const float4*)(wp3 + k);
        DOT4(acc[0][0], h0, w0); DOT4(acc[0][1], h0, w1); DOT4(acc[0][2], h0, w2); DOT4(acc[0][3], h0, w3);
        DOT4(acc[1][0], h1, w0); DOT4(acc[1][1], h1, w1); DOT4(acc[1][2], h1, w2); DOT4(acc[1][3], h1, w3);
        DOT4(acc[2][0], h2, w0); DOT4(acc[2][1], h2, w1); DOT4(acc[2][2], h2, w2); DOT4(acc[2][3], h2, w3);
        DOT4(acc[3][0], h3, w0); DOT4(acc[3][1], h3, w1); DOT4(acc[3][2], h3, w2); DOT4(acc[3][3], h3, w3);
      }
      // reduce over 8 k-groups (lane bits 0..2)
#pragma unroll
      for (int rr = 0; rr < 4; rr++)
#pragma unroll
        for (int cc = 0; cc < 4; cc++) {
          float v = acc[rr][cc];
          v += __shfl_xor(v, 1); v += __shfl_xor(v, 2); v += __shfl_xor(v, 4);
          acc[rr][cc] = v;
        }
      float s0v = 0.f, s1v = 0.f;
#pragma unroll
      for (int rr = 0; rr < 2; rr++)
#pragma unroll
        for (int cc = 0; cc < 4; cc++) {
          s0v = (kg == rr * 4 + cc) ? acc[rr][cc] : s0v;
          s1v = (kg == rr * 4 + cc) ? acc[rr + 2][cc] : s1v;
        }
      float o1 = tanhf(a1 + s0v);
      float o2 = tanhf(a2 + s1v);
      float* hw = a.dst + (size_t)(((s + 1) & 1) * 4 + dir) * B * H;
      stC(hw + (size_t)(b0 + r1) * H + nlane, o1);
      stC(hw + (size_t)(b0 + r2) * H + nlane, o2);
      relF(U, g16 + ntile, (unsigned)(s + 1));
      // l0 only consumed after grid barrier 1 (fenced) -> plain stores, deferred
      a.l0[((size_t)t * B + (b0 + r1)) * 1024 + dir * H + nlane] = o1;
      a.l0[((size_t)t * B + (b0 + r2)) * 1024 + dir * H + nlane] = o2;
    }
  }
  { unsigned* g = a.ctr + 40; bumpF(g); waitcF(g, 256u); }  // grid barrier 1

  //===================== ENC1 INPUT PROJECTION (in-place G1) ================
  {
    float* xl = sm;          // [16][1028]
    float* wl = sm + 16448;  // [64][260]
    const int kg = tid & 3;
    const int ci = (tid >> 2) & 15;
    const int ri = tid >> 6;
    for (int rt = 0; rt < 4; rt++) {
      int row0 = (bx * 4 + rt) * 16;
      __syncthreads();
      stage<1024, 1024>(a.l0 + (size_t)row0 * 1024, xl, 16, 1028);
      __syncthreads();
      for (int nc = 0; nc < 16; nc++) {
        const int nb = nc * 64 + ci * 4 + kg;
        float biasv = a.ebih[(2 + (nb >> 9)) * H + (nb & 511)] +
                      a.ebhh[(2 + (nb >> 9)) * H + (nb & 511)];
        float acc[4][4];
#pragma unroll
        for (int rr = 0; rr < 4; rr++)
#pragma unroll
          for (int cc = 0; cc < 4; cc++) acc[rr][cc] = 0.f;

        for (int kp = 0; kp < 4; kp++) {
          __syncthreads();
          stage<256, 1024>(a.eWih1 + (size_t)(nc * 64) * 1024 + kp * 256, wl, 64, 260);
          __syncthreads();
          const float* xp0 = xl + (ri * 4 + 0) * 1028 + kp * 256 + kg * 4;
          const float* xp1 = xp0 + 1028;
          const float* xp2 = xp0 + 2 * 1028;
          const float* xp3 = xp0 + 3 * 1028;
          const float* wq0 = wl + (ci * 4 + 0) * 260 + kg * 4;
          const float* wq1 = wq0 + 260;
          const float* wq2 = wq0 + 2 * 260;
          const float* wq3 = wq0 + 3 * 260;
#pragma unroll 4
          for (int i = 0; i < 16; i++) {
            const int k = i * 16;
            float4 x0 = *(const float4*)(xp0 + k);
            float4 x1 = *(const float4*)(xp1 + k);
            float4 x2 = *(const float4*)(xp2 + k);
            float4 x3 = *(const float4*)(xp3 + k);
            float4 w0 = *(const float4*)(wq0 + k);
            float4 w1 = *(const float4*)(wq1 + k);
            float4 w2 = *(const float4*)(wq2 + k);
            float4 w3 = *(const float4*)(wq3 + k);
            DOT4(acc[0][0], x0, w0); DOT4(acc[0][1], x0, w1); DOT4(acc[0][2], x0, w2); DOT4(acc[0][3], x0, w3);
            DOT4(acc[1][0], x1, w0); DOT4(acc[1][1], x1, w1); DOT4(acc[1][2], x1, w2); DOT4(acc[1][3], x1, w3);
            DOT4(acc[2][0], x2, w0); DOT4(acc[2][1], x2, w1); DOT4(acc[2][2], x2, w2); DOT4(acc[2][3], x2, w3);
            DOT4(acc[3][0], x3, w0); DOT4(acc[3][1], x3, w1); DOT4(acc[3][2], x3, w2); DOT4(acc[3][3], x3, w3);
          }
        }
#pragma unroll
        for (int rr = 0; rr < 4; rr++)
#pragma unroll
          for (int cc = 0; cc < 4; cc++) {
            float v = acc[rr][cc];
            v += __shfl_xor(v, 1); v += __shfl_xor(v, 2);
            acc[rr][cc] = v;
          }
        float o0 = 0.f, o1 = 0.f, o2 = 0.f, o3 = 0.f;
#pragma unroll
        for (int cc = 0; cc < 4; cc++) {
          o0 = (kg == cc) ? acc[0][cc] : o0;
          o1 = (kg == cc) ? acc[1][cc] : o1;
          o2 = (kg == cc) ? acc[2][cc] : o2;
          o3 = (kg == cc) ? acc[3][cc] : o3;
        }
        float* gr = a.l0 + (size_t)(row0 + ri * 4) * 1024 + nb;
        gr[0]        = o0 + biasv;
        gr[1024]     = o1 + biasv;
        gr[2 * 1024] = o2 + biasv;
        gr[3 * 1024] = o3 + biasv;
      }
    }
  }
  { unsigned* g = a.ctr + 40; bumpF(g); waitcF(g, 512u); }  // grid barrier 2

  //========================= ENCODER LAYER 1 ================================
  // Same slots as E0, monotone continuation: target T+s, set T+s+1 (129..256).
  {
    const int grp = bx & 15, mem = bx >> 4;
    const int dir = grp >> 3, btile = grp & 7, ntile = mem;
    const int b0 = btile * 16, n0 = ntile * 32;
    const int kg = tid & 7;
    const int ni = (tid >> 3) & 7;
    const int bi = tid >> 6;
    float* wl = sm;
    float* hl = sm + 16512;
    const int g16 = (dir * 8 + btile) * 16;

    stage16(a.eWhh1 + (size_t)(dir * H + n0) * H, wl);
    stage16(a.eWhh1 + (size_t)(dir * H + n0 + 16) * H, wl + 16 * 516);

    const int nlane = n0 + ni * 4 + (kg & 3);
    const int r1 = bi * 4 + (kg >> 2);
    const int r2 = r1 + 2;

    const float* hp0 = hl + (bi * 4 + 0) * 516 + kg * 4;
    const float* hp1 = hp0 + 516;
    const float* hp2 = hp0 + 2 * 516;
    const float* hp3 = hp0 + 3 * 516;
    const float* wp0 = wl + (ni * 4 + 0) * 516 + kg * 4;
    const float* wp1 = wp0 + 516;
    const float* wp2 = wp0 + 2 * 516;
    const float* wp3 = wp0 + 3 * 516;

    for (int s = 0; s < T; s++) {
      int t = dir ? (T - 1 - s) : s;
      // prefetch G1 gate values (l0 immutable after grid barrier 2) pre-wait
      float a1 = a.l0[((size_t)t * B + (b0 + r1)) * 1024 + dir * H + nlane];
      float a2 = a.l0[((size_t)t * B + (b0 + r2)) * 1024 + dir * H + nlane];

      if (s) waitF<16>(U, g16, (unsigned)(T + s)); else __syncthreads();
      stageC16(a.dst + ((size_t)((s & 1) * 4 + 2 + dir) * B + b0) * H, hl);
      __syncthreads();

      float acc[4][4];
#pragma unroll
      for (int rr = 0; rr < 4; rr++)
#pragma unroll
        for (int cc = 0; cc < 4; cc++) acc[rr][cc] = 0.f;

#pragma unroll 4
      for (int i = 0; i < 16; i++) {
        const int k = i * 32;
        float4 h0 = *(const float4*)(hp0 + k);
        float4 h1 = *(const float4*)(hp1 + k);
        float4 h2 = *(const float4*)(hp2 + k);
        float4 h3 = *(const float4*)(hp3 + k);
        float4 w0 = *(const float4*)(wp0 + k);
        float4 w1 = *(const float4*)(wp1 + k);
        float4 w2 = *(const float4*)(wp2 + k);
        float4 w3 = *(const float4*)(wp3 + k);
        DOT4(acc[0][0], h0, w0); DOT4(acc[0][1], h0, w1); DOT4(acc[0][2], h0, w2); DOT4(acc[0][3], h0, w3);
        DOT4(acc[1][0], h1, w0); DOT4(acc[1][1], h1, w1); DOT4(acc[1][2], h1, w2); DOT4(acc[1][3], h1, w3);
        DOT4(acc[2][0], h2, w0); DOT4(acc[2][1], h2, w1); DOT4(acc[2][2], h2, w2); DOT4(acc[2][3], h2, w3);
        DOT4(acc[3][0], h3, w0); DOT4(acc[3][1], h3, w1); DOT4(acc[3][2], h3, w2); DOT4(acc[3][3], h3, w3);
      }
#pragma unroll
      for (int rr = 0; rr < 4; rr++)
#pragma unroll
        for (int cc = 0; cc < 4; cc++) {
          float v = acc[rr][cc];
          v += __shfl_xor(v, 1); v += __shfl_xor(v, 2); v += __shfl_xor(v, 4);
          acc[rr][cc] = v;
        }
      float s0v = 0.f, s1v = 0.f;
#pragma unroll
      for (int rr = 0; rr < 2; rr++)
#pragma unroll
        for (int cc = 0; cc < 4; cc++) {
          s0v = (kg == rr * 4 + cc) ? acc[rr][cc] : s0v;
          s1v = (kg == rr * 4 + cc) ? acc[rr + 2][cc] : s1v;
        }
      float o1 = tanhf(a1 + s0v);
      float o2 = tanhf(a2 + s1v);
      float* hw = a.dst + (size_t)(((s + 1) & 1) * 4 + 2 + dir) * B * H;
      stC(hw + (size_t)(b0 + r1) * H + nlane, o1);
      stC(hw + (size_t)(b0 + r2) * H + nlane, o2);
      relF(U, g16 + ntile, (unsigned)(T + s + 1));
    }
  }
  { unsigned* g = a.ctr + 40; bumpF(g); waitcF(g, 768u); }  // grid barrier 3

  //============================== DECODER ===================================
  // ROUND-4 DECODER VERBATIM except flags: slot = btile*32 + ntile (0..255),
  // target 2T+m, set 2T+m+1 (257..384). After E1 all slots hold 256 exactly.
  {
    const int btile = bx & 7, ntile = bx >> 3;
    const int b0 = btile * 16, n0 = ntile * 16;
    const int j = tid & 15, bl = tid >> 4;   // mapping for xin/lin sections
    const int kg = tid & 15;                 // lane bits 0..3
    const int ni = (tid >> 4) & 3;           // lane bits 4..5
    const int bi = tid >> 6;                 // wave id, uniform
    float* whh  = sm;           // [16][516]
    float* wir  = sm + 8256;    // [16][516]
    float* hlc  = sm + 16512;   // [16][516] old state of current layer
    float* hin  = sm + 24768;   // [16][516] prev-layer new state (or h3 at l==0)
    float* xinL = sm + 33024;   // [16][4]
    const int g32 = btile * 32;

    const int nlane = n0 + ni * 4 + (kg & 3);
    const int rloc  = bi * 4 + (kg >> 2);
    float w00 = a.dWih0[nlane * 3 + 0], w01 = a.dWih0[nlane * 3 + 1], w02 = a.dWih0[nlane * 3 + 2];
    float bias0 = a.dbih[0 * H + nlane] + a.dbhh[0 * H + nlane];
    float bias1 = a.dbih[1 * H + nlane] + a.dbhh[1 * H + nlane];
    float bias2 = a.dbih[2 * H + nlane] + a.dbhh[2 * H + nlane];
    float bias3 = a.dbih[3 * H + nlane] + a.dbhh[3 * H + nlane];

    const float* hp0 = hlc + (bi * 4 + 0) * 516 + kg * 4;
    const float* hp1 = hp0 + 516;
    const float* hp2 = hp0 + 2 * 516;
    const float* hp3 = hp0 + 3 * 516;
    const float* ip0 = hin + (bi * 4 + 0) * 516 + kg * 4;
    const float* ip1 = ip0 + 516;
    const float* ip2 = ip0 + 2 * 516;
    const float* ip3 = ip0 + 3 * 516;
    const float* wp0 = whh + (ni * 4 + 0) * 516 + kg * 4;
    const float* wp1 = wp0 + 516;
    const float* wp2 = wp0 + 2 * 516;
    const float* wp3 = wp0 + 3 * 516;
    const float* up0 = wir + (ni * 4 + 0) * 516 + kg * 4;
    const float* up1 = up0 + 516;
    const float* up2 = up0 + 2 * 516;
    const float* up3 = up0 + 3 * 516;

    // prologue prefetch for m=0 (visible via grid barrier 3's acquire)
    stage16(a.dWhh + (size_t)(0 * H + n0) * H, whh);
    stageC16(a.dst + ((size_t)(0 * 4 + 0) * B + b0) * H, hlc);

    for (int m = 0; m < 128; m++) {
      int s = m >> 2, l = m & 3;
      int p = s & 1, q = 1 - p;
      if (m) waitF<32>(U, g32, (unsigned)(2 * T + m)); else __syncthreads();

      // only the m-1-produced buffer is staged post-wait
      if (l) {
        stageC16(a.dst + ((size_t)(q * 4 + (l - 1)) * B + b0) * H, hin);
      } else if (s) {
        stageC16(a.dst + ((size_t)(p * 4 + 3) * B + b0) * H, hin);  // h3
      }
      __syncthreads();

      if (l == 0) {
        if (s == 0) {
          if (j == 0) {
            const float* xr = a.x + ((size_t)(b0 + bl) * T + (T - 1)) * 3;
            float v0 = xr[0], v1 = xr[1], v2 = xr[2];
            xinL[bl * 4 + 0] = v0; xinL[bl * 4 + 1] = v1; xinL[bl * 4 + 2] = v2;
            if (ntile == 0) {
              float* xw = a.xing + (size_t)(b0 + bl) * 4;  // parity 0
              stC(xw + 0, v0); stC(xw + 1, v1); stC(xw + 2, v2);
            }
          }
        } else {
          const float* h3r = hin + bl * 516;
          float v = 0.f;
          for (int k = j; k < H; k += 16) v += h3r[k] * a.linW[k];
          v += __shfl_xor(v, 8); v += __shfl_xor(v, 4);
          v += __shfl_xor(v, 2); v += __shfl_xor(v, 1);
          float o0 = v + a.linb[0];
          const float* xp = a.xing + ((size_t)((s - 1) & 1) * B + (b0 + bl)) * 4;
          float sv1 = ldC(xp + 0) - o0;
          float sv2 = ldC(xp + 1) - sv1;
          if (j == 0) {
            xinL[bl * 4 + 0] = o0; xinL[bl * 4 + 1] = sv1; xinL[bl * 4 + 2] = sv2;
            if (ntile == 0) {
              float* xw = a.xing + ((size_t)(s & 1) * B + (b0 + bl)) * 4;
              stC(xw + 0, o0); stC(xw + 1, sv1); stC(xw + 2, sv2);
              a.out[(size_t)(b0 + bl) * TGT + (s - 1)] = o0;
            }
          }
        }
        __syncthreads();
      }

      float acc[4][4];
#pragma unroll
      for (int rr = 0; rr < 4; rr++)
#pragma unroll
        for (int cc = 0; cc < 4; cc++) acc[rr][cc] = 0.f;

      if (l) {
#pragma unroll 2
        for (int i = 0; i < 8; i++) {
          const int k = i * 64;
          float4 h0 = *(const float4*)(hp0 + k);
          float4 h1 = *(const float4*)(hp1 + k);
          float4 h2 = *(const float4*)(hp2 + k);
          float4 h3 = *(const float4*)(hp3 + k);
          float4 i0 = *(const float4*)(ip0 + k);
          float4 i1 = *(const float4*)(ip1 + k);
          float4 i2 = *(const float4*)(ip2 + k);
          float4 i3 = *(const float4*)(ip3 + k);
          float4 w0 = *(const float4*)(wp0 + k);
          float4 w1 = *(const float4*)(wp1 + k);
          float4 w2 = *(const float4*)(wp2 + k);
          float4 w3 = *(const float4*)(wp3 + k);
          float4 u0 = *(const float4*)(up0 + k);
          float4 u1 = *(const float4*)(up1 + k);
          float4 u2 = *(const float4*)(up2 + k);
          float4 u3 = *(const float4*)(up3 + k);
          DOT4B(acc[0][0], h0, w0, i0, u0); DOT4B(acc[0][1], h0, w1, i0, u1);
          DOT4B(acc[0][2], h0, w2, i0, u2); DOT4B(acc[0][3], h0, w3, i0, u3);
          DOT4B(acc[1][0], h1, w0, i1, u0); DOT4B(acc[1][1], h1, w1, i1, u1);
          DOT4B(acc[1][2], h1, w2, i1, u2); DOT4B(acc[1][3], h1, w3, i1, u3);
          DOT4B(acc[2][0], h2, w0, i2, u0); DOT4B(acc[2][1], h2, w1, i2, u1);
          DOT4B(acc[2][2], h2, w2, i2, u2); DOT4B(acc[2][3], h2, w3, i2, u3);
          DOT4B(acc[3][0], h3, w0, i3, u0); DOT4B(acc[3][1], h3, w1, i3, u1);
          DOT4B(acc[3][2], h3, w2, i3, u2); DOT4B(acc[3][3], h3, w3, i3, u3);
        }
      } else {
#pragma unroll 2
        for (int i = 0; i < 8; i++) {
          const int k = i * 64;
          float4 h0 = *(const float4*)(hp0 + k);
          float4 h1 = *(const float4*)(hp1 + k);
          float4 h2 = *(const float4*)(hp2 + k);
          float4 h3 = *(const float4*)(hp3 + k);
          float4 w0 = *(const float4*)(wp0 + k);
          float4 w1 = *(const float4*)(wp1 + k);
          float4 w2 = *(const float4*)(wp2 + k);
          float4 w3 = *(const float4*)(wp3 + k);
          DOT4(acc[0][0], h0, w0); DOT4(acc[0][1], h0, w1); DOT4(acc[0][2], h0, w2); DOT4(acc[0][3], h0, w3);
          DOT4(acc[1][0], h1, w0); DOT4(acc[1][1], h1, w1); DOT4(acc[1][2], h1, w2); DOT4(acc[1][3], h1, w3);
          DOT4(acc[2][0], h2, w0); DOT4(acc[2][1], h2, w1); DOT4(acc[2][2], h2, w2); DOT4(acc[2][3], h2, w3);
          DOT4(acc[3][0], h3, w0); DOT4(acc[3][1], h3, w1); DOT4(acc[3][2], h3, w2); DOT4(acc[3][3], h3, w3);
        }
      }
      // reduce over 16 k-groups (lane bits 0..3)
#pragma unroll
      for (int rr = 0; rr < 4; rr++)
#pragma unroll
        for (int cc = 0; cc < 4; cc++) {
          float v = acc[rr][cc];
          v += __shfl_xor(v, 1); v += __shfl_xor(v, 2);
          v += __shfl_xor(v, 4); v += __shfl_xor(v, 8);
          acc[rr][cc] = v;
        }
      float sv = 0.f;
#pragma unroll
      for (int rr = 0; rr < 4; rr++)
#pragma unroll
        for (int cc = 0; cc < 4; cc++)
          sv = (kg == rr * 4 + cc) ? acc[rr][cc] : sv;

      float bs = (l == 0) ? bias0 : (l == 1) ? bias1 : (l == 2) ? bias2 : bias3;
      float at = bs;
      if (l == 0)
        at += xinL[rloc * 4 + 0] * w00 + xinL[rloc * 4 + 1] * w01 + xinL[rloc * 4 + 2] * w02;
      float hnew = tanhf(at + sv);
      stC(a.dst + ((size_t)(q * 4 + l) * B + (b0 + rloc)) * H + nlane, hnew);
      relF(U, g32 + ntile, (unsigned)(2 * T + m + 1));

      // prefetch next step's weights + hlc (released >= 1 step ago) while
      // others are still finishing round m
      if (m < 127) {
        int m2 = m + 1, l2 = m2 & 3, s2 = m2 >> 2, p2 = s2 & 1;
        stage16(a.dWhh + (size_t)(l2 * H + n0) * H, whh);
        if (l2)
          stage16(a.dWihr + (size_t)((l2 - 1) * H + n0) * H, wir);
        stageC16(a.dst + ((size_t)(p2 * 4 + l2) * B + b0) * H, hlc);
      }
    }

    if (ntile == 0) {  // final output column t=31 from dstate[0][3]
      waitF<32>(U, g32, (unsigned)(2 * T + 128));
      const float* h3g = a.dst + ((size_t)(0 * 4 + 3) * B + (b0 + bl)) * H;
      float v = 0.f;
      for (int k = j; k < H; k += 16) v += ldC(h3g + k) * a.linW[k];
      v += __shfl_xor(v, 8); v += __shfl_xor(v, 4);
      v += __shfl_xor(v, 2); v += __shfl_xor(v, 1);
      if (j == 0) a.out[(size_t)(b0 + bl) * TGT + 31] = v + a.linb[0];
    }
  }
}

#undef DOT4
#undef DOT4B

// ---------------------------------------------------------------------------
extern "C" void kernel_launch(void* const* d_in, const int* in_sizes, int n_in,
                              void* d_out, int out_size, void* d_ws, size_t ws_size,
                              hipStream_t stream) {
  // ws layout (~66.0 MB): dstate 2MB | xing+flags 4KB | ctr 256B | l0/G1 64MB
  float* dst  = (float*)d_ws;
  float* xing = dst + 2 * 4 * B * H;
  unsigned* ctr = (unsigned*)((char*)d_ws + 2101248);
  float* l0 = (float*)((char*)d_ws + 2101504);

  kinit<<<256, 256, 0, stream>>>(dst, ctr);

  Args args;
  args.x     = (const float*)d_in[0];
  args.eWih0 = (const float*)d_in[2];
  args.eWhh0 = (const float*)d_in[3];
  args.eWih1 = (const float*)d_in[4];
  args.eWhh1 = (const float*)d_in[5];
  args.ebih  = (const float*)d_in[6];
  args.ebhh  = (const float*)d_in[7];
  args.dWih0 = (const float*)d_in[8];
  args.dWihr = (const float*)d_in[9];
  args.dWhh  = (const float*)d_in[10];
  args.dbih  = (const float*)d_in[11];
  args.dbhh  = (const float*)d_in[12];
  args.linW  = (const float*)d_in[13];
  args.linb  = (const float*)d_in[14];
  args.dst = dst; args.xing = xing; args.l0 = l0; args.ctr = ctr;
  args.out = (float*)d_out;

  void* kp[] = { &args };
  hipLaunchCooperativeKernel((void*)birnn_all, dim3(256), dim3(256), kp, 0, stream);
}